// Round 3
// baseline (983.945 us; speedup 1.0000x reference)
//
#include <hip/hip_runtime.h>
#include <math.h>

#define TOK   8192
#define DDIM  1024
#define HDIM  4096
#define NEXP  8
#define CAP   18432   /* 16384 + 8*256 = 72*256 */
#define NMT   72
#define BM    256
#define BN    256
#define BK    64      /* elems = 128 bytes */

typedef __attribute__((ext_vector_type(8))) short  bfrag;
typedef __attribute__((ext_vector_type(4))) float  ffrag;
typedef __attribute__((ext_vector_type(8))) unsigned short us8;

__device__ __forceinline__ unsigned short f2bf(float f) {
  unsigned int u = __float_as_uint(f);
  u = (u + 0x7FFFu + ((u >> 16) & 1u)) >> 16;   // RNE
  return (unsigned short)u;
}

__device__ __forceinline__ void gll16(const void* g, void* l) {
  __builtin_amdgcn_global_load_lds(
      (const __attribute__((address_space(1))) unsigned int*)g,
      (__attribute__((address_space(3))) unsigned int*)l,
      16, 0, 0);
}

// ---------------- W [R][C] fp32 -> WT [C][R] bf16 (per expert batch z) -------
__global__ __launch_bounds__(256) void transpose_cvt(const float* __restrict__ in,
                                                     unsigned short* __restrict__ out,
                                                     int R, int C) {
  const size_t bo = (size_t)blockIdx.z * R * C;
  in += bo; out += bo;
  int r0 = blockIdx.y * 64, c0 = blockIdx.x * 64;
  __shared__ float t[64][65];
  int tr  = threadIdx.x >> 4;
  int tc4 = (threadIdx.x & 15) * 4;
#pragma unroll
  for (int it = 0; it < 4; ++it) {
    int r = tr + it * 16;
    float4 v = *(const float4*)&in[(size_t)(r0 + r) * C + c0 + tc4];
    t[r][tc4 + 0] = v.x; t[r][tc4 + 1] = v.y; t[r][tc4 + 2] = v.z; t[r][tc4 + 3] = v.w;
  }
  __syncthreads();
#pragma unroll
  for (int it = 0; it < 4; ++it) {
    int oc = tr + it * 16;
    int og = tc4;
    ushort4 o = { f2bf(t[og + 0][oc]), f2bf(t[og + 1][oc]),
                  f2bf(t[og + 2][oc]), f2bf(t[og + 3][oc]) };
    *(ushort4*)&out[(size_t)(c0 + oc) * R + r0 + og] = o;
  }
}

// ------- gate: logits, top-2, softmax, histogram; fused x fp32->bf16 -------
__global__ __launch_bounds__(64) void gate_kernel(const float* __restrict__ x,
                                                  const float* __restrict__ Wg,
                                                  const float* __restrict__ bg,
                                                  unsigned short* __restrict__ xb,
                                                  int* __restrict__ topi,
                                                  float* __restrict__ topw,
                                                  int* __restrict__ cnt) {
  int t = blockIdx.x, l = threadIdx.x;
  const float4* xr = (const float4*)(x + (size_t)t * DDIM);
  ushort4* xo = (ushort4*)(xb + (size_t)t * DDIM);
  const float4* wg = (const float4*)Wg;
  float acc[8];
#pragma unroll
  for (int e = 0; e < 8; ++e) acc[e] = 0.f;
#pragma unroll
  for (int g = 0; g < 4; ++g) {
    int idx = g * 64 + l;
    float4 xv = xr[idx];
    xo[idx] = (ushort4){ f2bf(xv.x), f2bf(xv.y), f2bf(xv.z), f2bf(xv.w) };
    int dbase = idx * 4;
    float xs[4] = { xv.x, xv.y, xv.z, xv.w };
#pragma unroll
    for (int c = 0; c < 4; ++c) {
      float4 w0 = wg[(dbase + c) * 2 + 0];
      float4 w1 = wg[(dbase + c) * 2 + 1];
      acc[0] += xs[c] * w0.x; acc[1] += xs[c] * w0.y;
      acc[2] += xs[c] * w0.z; acc[3] += xs[c] * w0.w;
      acc[4] += xs[c] * w1.x; acc[5] += xs[c] * w1.y;
      acc[6] += xs[c] * w1.z; acc[7] += xs[c] * w1.w;
    }
  }
#pragma unroll
  for (int off = 32; off >= 1; off >>= 1)
#pragma unroll
    for (int e = 0; e < 8; ++e) acc[e] += __shfl_down(acc[e], off);
  if (l == 0) {
    float v[8];
#pragma unroll
    for (int e = 0; e < 8; ++e) v[e] = acc[e] + bg[e];
    int i0 = 0;
#pragma unroll
    for (int e = 1; e < 8; ++e) if (v[e] > v[i0]) i0 = e;
    int i1 = -1;
#pragma unroll
    for (int e = 0; e < 8; ++e) if (e != i0 && (i1 < 0 || v[e] > v[i1])) i1 = e;
    float e1 = expf(v[i1] - v[i0]);
    float s = 1.f + e1;
    topi[t * 2 + 0] = i0; topi[t * 2 + 1] = i1;
    topw[t * 2 + 0] = 1.f / s; topw[t * 2 + 1] = e1 / s;
    atomicAdd(&cnt[i0], 1);
    atomicAdd(&cnt[i1], 1);
  }
}

// ---------------- offsets: 256-aligned exclusive scan ----------------
__global__ void scan_kernel(const int* __restrict__ cnt, int* __restrict__ offsets) {
  if (threadIdx.x == 0 && blockIdx.x == 0) {
    int o = 0;
#pragma unroll
    for (int e = 0; e < NEXP; ++e) {
      offsets[e] = o;
      o += ((cnt[e] + 255) >> 8) << 8;
    }
    offsets[NEXP] = o;
  }
}

// ---------------- assign rows ----------------
__global__ __launch_bounds__(256) void assign_kernel(const int* __restrict__ topi,
                                                     const float* __restrict__ topw,
                                                     const int* __restrict__ offsets,
                                                     int* __restrict__ cursor,
                                                     int* __restrict__ token_of,
                                                     float* __restrict__ wt_of) {
  int id = blockIdx.x * 256 + threadIdx.x;
  if (id >= TOK * 2) return;
  int e = topi[id];
  int slot = atomicAdd(&cursor[e], 1);
  int row = offsets[e] + slot;
  token_of[row] = id >> 1;
  wt_of[row] = topw[id];
}

// ------------- grouped GEMM: 256x256 tile, 4-phase counted-vmcnt -------------
// A: bf16 [rows][K]; INDIRECT: staged row -> token_of gather.
// B: bf16 [NEXP][N][K] (k-contiguous).
// GELU: hout[row][N] = bf16 gelu(acc+bias) via LDS-staged coalesced store.
// else: atomicAdd out[token][col] += wt * (acc + bias)  (deterministic: 2 adds).
template<bool INDIRECT, bool GELU>
__global__ __launch_bounds__(512, 2)
void moe_gemm(const unsigned short* __restrict__ A, int lda,
              const unsigned short* __restrict__ B0,
              const float* __restrict__ bias0,
              unsigned short* __restrict__ hout,
              float* __restrict__ out,
              int N, int K,
              const int* __restrict__ offsets,
              const int* __restrict__ token_of,
              const float* __restrict__ wt_of) {
  // XCD-chunked bijective swizzle (nwg % 8 == 0 for both grids)
  int nwg = gridDim.x * gridDim.y;
  int orig = blockIdx.y * gridDim.x + blockIdx.x;
  int vid = (orig & 7) * (nwg >> 3) + (orig >> 3);
  int bx = vid % gridDim.x, by = vid / gridDim.x;

  int row0 = by * BM;
  if (row0 >= offsets[NEXP]) return;
  int e = 0;
  while (row0 >= offsets[e + 1]) ++e;
  const unsigned short* B = B0 + (size_t)e * N * K;
  const float* bias = bias0 + (size_t)e * N;
  int n0 = bx * BN;

  // A tiles: sm[0 .. 65536)  = [2 buf][256 rows][128 B]
  // B tiles: sm[65536 .. 131072)
  __shared__ __align__(16) char sm[131072];

  int tid = threadIdx.x;
  int w = tid >> 6, l = tid & 63;
  int lrow = l & 15, kq = l >> 4;
  int wm = w & 1, wn = w >> 1;            // 2 x 4 wave grid; wave C = 128x64

  // staging: per thread 4 A-chunks + 4 B-chunks (16B) per K-tile.
  // LDS dest is linear (wave-uniform base + lane*16); READ side XORs the
  // 16B-chunk col with (row&7), so the global SOURCE is inverse-swizzled.
  const char* srcA[4];
  const char* srcB[4];
#pragma unroll
  for (int li = 0; li < 4; ++li) {
    int grp = w * 4 + li;                 // 8-row group 0..31
    int gr  = grp * 8 + (l >> 3);         // tile row 0..255
    int c   = (l & 7) ^ (gr & 7);         // inverse-swizzled chunk col
    int arow;
    if (INDIRECT) {
      int t0 = token_of[row0 + gr];
      arow = t0 < 0 ? 0 : t0;
    } else {
      arow = row0 + gr;
    }
    srcA[li] = (const char*)(A + (size_t)arow * lda) + c * 16;
    srcB[li] = (const char*)(B + (size_t)(n0 + gr) * K) + c * 16;
  }

  auto issue = [&](int t) {
    int bufo = (t & 1) * 32768;
    int kb = t * 128;
#pragma unroll
    for (int li = 0; li < 4; ++li) {
      int dst = (w * 4 + li) * 1024;
      gll16(srcA[li] + kb, sm + bufo + dst);
      gll16(srcB[li] + kb, sm + 65536 + bufo + dst);
    }
  };
  auto rdA = [&](int bufo, int mi, int ks) -> bfrag {
    int row = wm * 128 + mi * 16 + lrow;
    int cc = (ks * 4 + kq) ^ (row & 7);
    return *(const bfrag*)(sm + bufo + row * 128 + cc * 16);
  };
  auto rdB = [&](int bufo, int nj, int ks) -> bfrag {
    int row = wn * 64 + nj * 16 + lrow;
    int cc = (ks * 4 + kq) ^ (row & 7);
    return *(const bfrag*)(sm + 65536 + bufo + row * 128 + cc * 16);
  };

  ffrag acc[8][4];
#pragma unroll
  for (int i = 0; i < 8; ++i)
#pragma unroll
    for (int j = 0; j < 4; ++j) acc[i][j] = (ffrag){0.f, 0.f, 0.f, 0.f};

  issue(0); issue(1);
  asm volatile("s_waitcnt vmcnt(8)" ::: "memory");
  __builtin_amdgcn_sched_barrier(0);
  __builtin_amdgcn_s_barrier();

  bfrag a[4][2], b[2][2];
  const int NKt = K / BK;
  for (int t = 0; t < NKt; ++t) {
    int bufo = (t & 1) * 32768;
    // ---- phase 0: quadrant (rows wm*128+0..63, cols wn*64+0..31) ----
#pragma unroll
    for (int mi = 0; mi < 4; ++mi) { a[mi][0] = rdA(bufo, mi, 0); a[mi][1] = rdA(bufo, mi, 1); }
#pragma unroll
    for (int nj = 0; nj < 2; ++nj) { b[nj][0] = rdB(bufo, nj, 0); b[nj][1] = rdB(bufo, nj, 1); }
    __builtin_amdgcn_s_barrier();
    __builtin_amdgcn_s_setprio(1);
#pragma unroll
    for (int mi = 0; mi < 4; ++mi)
#pragma unroll
      for (int nj = 0; nj < 2; ++nj) {
        acc[mi][nj] = __builtin_amdgcn_mfma_f32_16x16x32_bf16(a[mi][0], b[nj][0], acc[mi][nj], 0, 0, 0);
        acc[mi][nj] = __builtin_amdgcn_mfma_f32_16x16x32_bf16(a[mi][1], b[nj][1], acc[mi][nj], 0, 0, 0);
      }
    __builtin_amdgcn_s_setprio(0);
    __builtin_amdgcn_s_barrier();
    // ---- phase 1: rows +64..127, same cols (load A1, reuse b) ----
#pragma unroll
    for (int mi = 0; mi < 4; ++mi) { a[mi][0] = rdA(bufo, mi + 4, 0); a[mi][1] = rdA(bufo, mi + 4, 1); }
    __builtin_amdgcn_s_barrier();
    __builtin_amdgcn_s_setprio(1);
#pragma unroll
    for (int mi = 0; mi < 4; ++mi)
#pragma unroll
      for (int nj = 0; nj < 2; ++nj) {
        acc[mi + 4][nj] = __builtin_amdgcn_mfma_f32_16x16x32_bf16(a[mi][0], b[nj][0], acc[mi + 4][nj], 0, 0, 0);
        acc[mi + 4][nj] = __builtin_amdgcn_mfma_f32_16x16x32_bf16(a[mi][1], b[nj][1], acc[mi + 4][nj], 0, 0, 0);
      }
    __builtin_amdgcn_s_setprio(0);
    __builtin_amdgcn_s_barrier();
    // ---- phase 2: rows +64..127, cols +32..63 (load B1, reuse a) ----
#pragma unroll
    for (int nj = 0; nj < 2; ++nj) { b[nj][0] = rdB(bufo, nj + 2, 0); b[nj][1] = rdB(bufo, nj + 2, 1); }
    __builtin_amdgcn_s_barrier();
    __builtin_amdgcn_s_setprio(1);
#pragma unroll
    for (int mi = 0; mi < 4; ++mi)
#pragma unroll
      for (int nj = 0; nj < 2; ++nj) {
        acc[mi + 4][nj + 2] = __builtin_amdgcn_mfma_f32_16x16x32_bf16(a[mi][0], b[nj][0], acc[mi + 4][nj + 2], 0, 0, 0);
        acc[mi + 4][nj + 2] = __builtin_amdgcn_mfma_f32_16x16x32_bf16(a[mi][1], b[nj][1], acc[mi + 4][nj + 2], 0, 0, 0);
      }
    __builtin_amdgcn_s_setprio(0);
    __builtin_amdgcn_s_barrier();
    // ---- phase 3: rows 0..63, cols +32..63 (reload A0, reuse b) ----
#pragma unroll
    for (int mi = 0; mi < 4; ++mi) { a[mi][0] = rdA(bufo, mi, 0); a[mi][1] = rdA(bufo, mi, 1); }
    __builtin_amdgcn_sched_barrier(0);
    __builtin_amdgcn_s_barrier();           // all waves done reading this buffer
    if (t + 2 < NKt) {
      issue(t + 2);                          // overwrite this buffer for tile t+2
      asm volatile("s_waitcnt vmcnt(8)" ::: "memory");   // tile t+1 landed
    } else if (t + 2 == NKt) {
      asm volatile("s_waitcnt vmcnt(0)" ::: "memory");   // last tile landed
    }
    __builtin_amdgcn_sched_barrier(0);
    __builtin_amdgcn_s_barrier();
    __builtin_amdgcn_s_setprio(1);
#pragma unroll
    for (int mi = 0; mi < 4; ++mi)
#pragma unroll
      for (int nj = 0; nj < 2; ++nj) {
        acc[mi][nj + 2] = __builtin_amdgcn_mfma_f32_16x16x32_bf16(a[mi][0], b[nj][0], acc[mi][nj + 2], 0, 0, 0);
        acc[mi][nj + 2] = __builtin_amdgcn_mfma_f32_16x16x32_bf16(a[mi][1], b[nj][1], acc[mi][nj + 2], 0, 0, 0);
      }
    __builtin_amdgcn_s_setprio(0);
    __builtin_amdgcn_s_barrier();
  }

  if (GELU) {
    __syncthreads();
    unsigned short* ht = (unsigned short*)sm;   // reuse as [256][256] bf16
#pragma unroll
    for (int nj = 0; nj < 4; ++nj) {
      int col = wn * 64 + nj * 16 + lrow;
      float bj = bias[n0 + col];
#pragma unroll
      for (int mi = 0; mi < 8; ++mi) {
        int rl = wm * 128 + mi * 16 + kq * 4;
#pragma unroll
        for (int r = 0; r < 4; ++r) {
          float v = acc[mi][nj][r] + bj;
          float z = 1.5957691216f * (v + 0.044715f * v * v * v);
          v = v / (1.0f + __expf(-z));
          ht[(rl + r) * 256 + col] = f2bf(v);
        }
      }
    }
    __syncthreads();
#pragma unroll
    for (int it = 0; it < 16; ++it) {
      int s = it * 512 + tid;
      int row = s >> 5, c = (s & 31) * 8;
      us8 v = *(const us8*)(ht + row * 256 + c);
      *(us8*)&hout[(size_t)(row0 + row) * N + n0 + c] = v;
    }
  } else {
#pragma unroll
    for (int mi = 0; mi < 8; ++mi) {
      int rbase = row0 + wm * 128 + mi * 16 + kq * 4;
#pragma unroll
      for (int r = 0; r < 4; ++r) {
        int tok = token_of[rbase + r];
        if (tok < 0) continue;
        float wt = wt_of[rbase + r];
        float* op = out + (size_t)tok * DDIM;
#pragma unroll
        for (int nj = 0; nj < 4; ++nj) {
          int col = n0 + wn * 64 + nj * 16 + lrow;
          atomicAdd(op + col, wt * (acc[mi][nj][r] + bias[col]));
        }
      }
    }
  }
}

extern "C" void kernel_launch(void* const* d_in, const int* in_sizes, int n_in,
                              void* d_out, int out_size, void* d_ws, size_t ws_size,
                              hipStream_t stream) {
  const float* x  = (const float*)d_in[0];
  const float* Wg = (const float*)d_in[1];
  const float* bg = (const float*)d_in[2];
  const float* W1 = (const float*)d_in[3];
  const float* b1 = (const float*)d_in[4];
  const float* W2 = (const float*)d_in[5];
  const float* b2 = (const float*)d_in[6];
  float* out = (float*)d_out;

  size_t off = 0;
  char* base = (char*)d_ws;
  auto alloc = [&](size_t bytes) -> void* {
    void* p = base + off;
    off += (bytes + 255) & ~(size_t)255;
    return p;
  };
  unsigned short* xb  = (unsigned short*)alloc((size_t)TOK * DDIM * 2);
  unsigned short* w1t = (unsigned short*)alloc((size_t)NEXP * HDIM * DDIM * 2);
  unsigned short* w2t = (unsigned short*)alloc((size_t)NEXP * DDIM * HDIM * 2);
  unsigned short* h   = (unsigned short*)alloc((size_t)CAP * HDIM * 2);
  int*   topi     = (int*)alloc((size_t)TOK * 2 * 4);
  float* topw     = (float*)alloc((size_t)TOK * 2 * 4);
  int*   token_of = (int*)alloc((size_t)CAP * 4);
  float* wt_of    = (float*)alloc((size_t)CAP * 4);
  int*   cnt      = (int*)alloc(32);
  int*   offsets  = (int*)alloc(64);
  int*   cursor   = (int*)alloc(32);
  if (off > ws_size) return;

  hipMemsetAsync(cnt, 0, 32, stream);
  hipMemsetAsync(cursor, 0, 32, stream);
  hipMemsetAsync(token_of, 0xFF, (size_t)CAP * 4, stream);
  hipMemsetAsync(out, 0, (size_t)TOK * DDIM * 4, stream);

  transpose_cvt<<<dim3(HDIM / 64, DDIM / 64, NEXP), 256, 0, stream>>>(W1, w1t, DDIM, HDIM);
  transpose_cvt<<<dim3(DDIM / 64, HDIM / 64, NEXP), 256, 0, stream>>>(W2, w2t, HDIM, DDIM);
  gate_kernel<<<TOK, 64, 0, stream>>>(x, Wg, bg, xb, topi, topw, cnt);
  scan_kernel<<<1, 64, 0, stream>>>(cnt, offsets);
  assign_kernel<<<(TOK * 2) / 256, 256, 0, stream>>>(topi, topw, offsets, cursor,
                                                     token_of, wt_of);

  moe_gemm<true, true><<<dim3(HDIM / BN, NMT), 512, 0, stream>>>(
      xb, DDIM, w1t, b1, h, nullptr, HDIM, DDIM, offsets, token_of, wt_of);
  moe_gemm<false, false><<<dim3(DDIM / BN, NMT), 512, 0, stream>>>(
      h, HDIM, w2t, b2, nullptr, out, DDIM, HDIM, offsets, token_of, wt_of);
}

// Round 4
// 831.385 us; speedup vs baseline: 1.1835x; 1.1835x over previous
//
#include <hip/hip_runtime.h>
#include <math.h>

#define TOK   8192
#define DDIM  1024
#define HDIM  4096
#define NEXP  8
#define CAP   17408   /* 16384 + 8*128 padding, = 136*128 */
#define NMT   136
#define BM    128
#define BN    128
#define BK    32

typedef __attribute__((ext_vector_type(8))) short  bfrag;
typedef __attribute__((ext_vector_type(4))) float  ffrag;
typedef __attribute__((ext_vector_type(8))) unsigned short us8;

__device__ __forceinline__ unsigned short f2bf(float f) {
  unsigned int u = __float_as_uint(f);
  u = (u + 0x7FFFu + ((u >> 16) & 1u)) >> 16;   // RNE
  return (unsigned short)u;
}

__device__ __forceinline__ void gll16(const unsigned short* g, unsigned short* l) {
  __builtin_amdgcn_global_load_lds(
      (const __attribute__((address_space(1))) unsigned int*)g,
      (__attribute__((address_space(3))) unsigned int*)l,
      16, 0, 0);
}

// ---------------- W [R][C] fp32 -> WT [C][R] bf16 (per expert batch z) -------
__global__ __launch_bounds__(256) void transpose_cvt(const float* __restrict__ in,
                                                     unsigned short* __restrict__ out,
                                                     int R, int C) {
  const size_t bo = (size_t)blockIdx.z * R * C;
  in += bo; out += bo;
  int r0 = blockIdx.y * 64, c0 = blockIdx.x * 64;
  __shared__ float t[64][65];
  int tr  = threadIdx.x >> 4;
  int tc4 = (threadIdx.x & 15) * 4;
#pragma unroll
  for (int it = 0; it < 4; ++it) {
    int r = tr + it * 16;
    float4 v = *(const float4*)&in[(size_t)(r0 + r) * C + c0 + tc4];
    t[r][tc4 + 0] = v.x; t[r][tc4 + 1] = v.y; t[r][tc4 + 2] = v.z; t[r][tc4 + 3] = v.w;
  }
  __syncthreads();
#pragma unroll
  for (int it = 0; it < 4; ++it) {
    int oc = tr + it * 16;
    int og = tc4;
    ushort4 o = { f2bf(t[og + 0][oc]), f2bf(t[og + 1][oc]),
                  f2bf(t[og + 2][oc]), f2bf(t[og + 3][oc]) };
    *(ushort4*)&out[(size_t)(c0 + oc) * R + r0 + og] = o;
  }
}

// ------- gate: logits, top-2, softmax, histogram; fused x fp32->bf16 -------
__global__ __launch_bounds__(64) void gate_kernel(const float* __restrict__ x,
                                                  const float* __restrict__ Wg,
                                                  const float* __restrict__ bg,
                                                  unsigned short* __restrict__ xb,
                                                  int* __restrict__ topi,
                                                  float* __restrict__ topw,
                                                  int* __restrict__ cnt) {
  int t = blockIdx.x, l = threadIdx.x;
  const float4* xr = (const float4*)(x + (size_t)t * DDIM);
  ushort4* xo = (ushort4*)(xb + (size_t)t * DDIM);
  const float4* wg = (const float4*)Wg;
  float acc[8];
#pragma unroll
  for (int e = 0; e < 8; ++e) acc[e] = 0.f;
#pragma unroll
  for (int g = 0; g < 4; ++g) {
    int idx = g * 64 + l;
    float4 xv = xr[idx];
    xo[idx] = (ushort4){ f2bf(xv.x), f2bf(xv.y), f2bf(xv.z), f2bf(xv.w) };
    int dbase = idx * 4;
    float xs[4] = { xv.x, xv.y, xv.z, xv.w };
#pragma unroll
    for (int c = 0; c < 4; ++c) {
      float4 w0 = wg[(dbase + c) * 2 + 0];
      float4 w1 = wg[(dbase + c) * 2 + 1];
      acc[0] += xs[c] * w0.x; acc[1] += xs[c] * w0.y;
      acc[2] += xs[c] * w0.z; acc[3] += xs[c] * w0.w;
      acc[4] += xs[c] * w1.x; acc[5] += xs[c] * w1.y;
      acc[6] += xs[c] * w1.z; acc[7] += xs[c] * w1.w;
    }
  }
#pragma unroll
  for (int off = 32; off >= 1; off >>= 1)
#pragma unroll
    for (int e = 0; e < 8; ++e) acc[e] += __shfl_down(acc[e], off);
  if (l == 0) {
    float v[8];
#pragma unroll
    for (int e = 0; e < 8; ++e) v[e] = acc[e] + bg[e];
    int i0 = 0;
#pragma unroll
    for (int e = 1; e < 8; ++e) if (v[e] > v[i0]) i0 = e;
    int i1 = -1;
#pragma unroll
    for (int e = 0; e < 8; ++e) if (e != i0 && (i1 < 0 || v[e] > v[i1])) i1 = e;
    float e1 = expf(v[i1] - v[i0]);
    float s = 1.f + e1;
    topi[t * 2 + 0] = i0; topi[t * 2 + 1] = i1;
    topw[t * 2 + 0] = 1.f / s; topw[t * 2 + 1] = e1 / s;
    atomicAdd(&cnt[i0], 1);
    atomicAdd(&cnt[i1], 1);
  }
}

// local 128-aligned exclusive scan of cnt (uniform, 8 entries)
__device__ __forceinline__ void local_scan(const int* __restrict__ cnt, int* offs) {
  int o = 0;
#pragma unroll
  for (int e = 0; e < NEXP; ++e) {
    offs[e] = o;
    o += ((cnt[e] + 127) >> 7) << 7;
  }
  offs[NEXP] = o;
}

// ---------------- assign rows ----------------
__global__ __launch_bounds__(256) void assign_kernel(const int* __restrict__ topi,
                                                     const float* __restrict__ topw,
                                                     const int* __restrict__ cnt,
                                                     int* __restrict__ cursor,
                                                     int* __restrict__ token_of,
                                                     float* __restrict__ wt_of) {
  int offs[NEXP + 1];
  local_scan(cnt, offs);
  int id = blockIdx.x * 256 + threadIdx.x;
  if (id >= TOK * 2) return;
  int e = topi[id];
  int slot = atomicAdd(&cursor[e], 1);
  int row = offs[e] + slot;
  token_of[row] = id >> 1;
  wt_of[row] = topw[id];
}

// ---------------- grouped GEMM (m97 structure, proven in r2) ----------------
// A: bf16 [rows][K] (INDIRECT: row -> token_of gather into [TOK][K])
// B: bf16 [NEXP][N][K] (k-contiguous)
// GELU: hout[row][N] = bf16 gelu(acc+bias), LDS-staged coalesced store.
// else: fused combine -- atomicAdd out[token][col] += wt*(acc+bias)
//       (exactly 2 commutative adds per output element).
template<bool INDIRECT, bool GELU, int N, int K>
__global__ __launch_bounds__(256)
void moe_gemm(const unsigned short* __restrict__ A,
              const unsigned short* __restrict__ B0,
              const float* __restrict__ bias0,
              unsigned short* __restrict__ hout,
              float* __restrict__ out,
              const int* __restrict__ cnt,
              const int* __restrict__ token_of,
              const float* __restrict__ wt_of) {
  int offs[NEXP + 1];
  local_scan(cnt, offs);

  // XCD-chunked bijective swizzle (nwg % 8 == 0 for both grids)
  int nwg = gridDim.x * gridDim.y;
  int orig = blockIdx.y * gridDim.x + blockIdx.x;
  int vid = (orig & 7) * (nwg >> 3) + (orig >> 3);
  int bx = vid % gridDim.x, by = vid / gridDim.x;

  int row0 = by * BM;
  if (row0 >= offs[NEXP]) return;
  int e = 0;
  while (row0 >= offs[e + 1]) ++e;
  const unsigned short* B = B0 + (size_t)e * N * K;
  const float* bias = bias0 + (size_t)e * N;
  int n0 = bx * BN;

  // 32 KB pool: As=[2][BM][BK], Bs=[2][BN][BK]; epilogue reuses as [BM][BN] bf16
  __shared__ __align__(16) unsigned short sm[16384];
#define AS_(buf, r, k) sm[(buf) * (BM * BK) + (r) * BK + (k)]
#define BS_(buf, r, k) sm[2 * (BM * BK) + (buf) * (BN * BK) + (r) * BK + (k)]

  int tid = threadIdx.x;
  int w = tid >> 6, l = tid & 63;
  int s0 = 2 * w, s1 = 2 * w + 1;        // each wave stages 2 of 8 16-row segments
  int rsub = l >> 2;                      // row within segment
  int cgrp = (l & 3) * 8;                 // k offset (8 bf16 = 16B)

  const unsigned short *srcA0, *srcA1;
  if (INDIRECT) {
    int t0 = token_of[row0 + s0 * 16 + rsub];
    int t1 = token_of[row0 + s1 * 16 + rsub];
    if (t0 < 0) t0 = 0;
    if (t1 < 0) t1 = 0;
    srcA0 = A + (size_t)t0 * K + cgrp;
    srcA1 = A + (size_t)t1 * K + cgrp;
  } else {
    srcA0 = A + (size_t)(row0 + s0 * 16 + rsub) * K + cgrp;
    srcA1 = A + (size_t)(row0 + s1 * 16 + rsub) * K + cgrp;
  }
  const unsigned short* srcB0 = B + (size_t)(n0 + s0 * 16 + rsub) * K + cgrp;
  const unsigned short* srcB1 = B + (size_t)(n0 + s1 * 16 + rsub) * K + cgrp;

  ffrag acc[4][4];
#pragma unroll
  for (int i = 0; i < 4; ++i)
#pragma unroll
    for (int j = 0; j < 4; ++j) acc[i][j] = (ffrag){0.f, 0.f, 0.f, 0.f};

  int lrow = l & 15, kq = l >> 4;
  int wm = w >> 1, wn = w & 1;

  auto stage = [&](int buf, int k0) {
    gll16(srcA0 + k0, &AS_(buf, s0 * 16, 0));
    gll16(srcA1 + k0, &AS_(buf, s1 * 16, 0));
    gll16(srcB0 + k0, &BS_(buf, s0 * 16, 0));
    gll16(srcB1 + k0, &BS_(buf, s1 * 16, 0));
  };
  auto compute = [&](int buf) {
    bfrag a[4], b[4];
#pragma unroll
    for (int i = 0; i < 4; ++i)
      a[i] = *(const bfrag*)&AS_(buf, wm * 64 + i * 16 + lrow, kq * 8);
#pragma unroll
    for (int j = 0; j < 4; ++j)
      b[j] = *(const bfrag*)&BS_(buf, wn * 64 + j * 16 + lrow, kq * 8);
#pragma unroll
    for (int i = 0; i < 4; ++i)
#pragma unroll
      for (int j = 0; j < 4; ++j)
        acc[i][j] = __builtin_amdgcn_mfma_f32_16x16x32_bf16(a[i], b[j], acc[i][j], 0, 0, 0);
  };

  stage(0, 0);
  __syncthreads();
  constexpr int nk = K / BK;
  int cur = 0;
  for (int kt = 0; kt < nk; ++kt) {
    if (kt + 1 < nk) stage(cur ^ 1, (kt + 1) * BK);
    compute(cur);
    __syncthreads();
    cur ^= 1;
  }

  if (GELU) {
#pragma unroll
    for (int j = 0; j < 4; ++j) {
      int col = wn * 64 + j * 16 + lrow;
      float bj = bias[n0 + col];
#pragma unroll
      for (int i = 0; i < 4; ++i) {
        int rloc = wm * 64 + i * 16 + kq * 4;
#pragma unroll
        for (int r = 0; r < 4; ++r) {
          float v = acc[i][j][r] + bj;
          // tanh-form GELU, sigmoid arrangement (stable both tails):
          float z = 1.5957691216f * (v + 0.044715f * v * v * v);
          v = v / (1.0f + __expf(-z));
          sm[(rloc + r) * BN + col] = f2bf(v);
        }
      }
    }
    __syncthreads();
#pragma unroll
    for (int it = 0; it < 8; ++it) {
      int c = it * 256 + tid;
      int row = c >> 4;
      int cc = (c & 15) * 8;
      us8 v = *(const us8*)&sm[row * BN + cc];
      *(us8*)&hout[(size_t)(row0 + row) * N + n0 + cc] = v;
    }
  } else {
#pragma unroll
    for (int i = 0; i < 4; ++i) {
      int rbase = row0 + wm * 64 + i * 16 + kq * 4;
#pragma unroll
      for (int r = 0; r < 4; ++r) {
        int tok = token_of[rbase + r];
        if (tok < 0) continue;
        float wt = wt_of[rbase + r];
        float* op = out + (size_t)tok * DDIM;
#pragma unroll
        for (int j = 0; j < 4; ++j) {
          int col = n0 + wn * 64 + j * 16 + lrow;
          atomicAdd(op + col, wt * (acc[i][j][r] + bias[col]));
        }
      }
    }
  }
#undef AS_
#undef BS_
}

extern "C" void kernel_launch(void* const* d_in, const int* in_sizes, int n_in,
                              void* d_out, int out_size, void* d_ws, size_t ws_size,
                              hipStream_t stream) {
  const float* x  = (const float*)d_in[0];
  const float* Wg = (const float*)d_in[1];
  const float* bg = (const float*)d_in[2];
  const float* W1 = (const float*)d_in[3];
  const float* b1 = (const float*)d_in[4];
  const float* W2 = (const float*)d_in[5];
  const float* b2 = (const float*)d_in[6];
  float* out = (float*)d_out;

  size_t off = 0;
  char* base = (char*)d_ws;
  auto alloc = [&](size_t bytes) -> void* {
    void* p = base + off;
    off += (bytes + 255) & ~(size_t)255;
    return p;
  };
  unsigned short* xb  = (unsigned short*)alloc((size_t)TOK * DDIM * 2);
  unsigned short* w1t = (unsigned short*)alloc((size_t)NEXP * HDIM * DDIM * 2);
  unsigned short* w2t = (unsigned short*)alloc((size_t)NEXP * DDIM * HDIM * 2);
  unsigned short* h   = (unsigned short*)alloc((size_t)CAP * HDIM * 2);
  int*   topi     = (int*)alloc((size_t)TOK * 2 * 4);
  float* topw     = (float*)alloc((size_t)TOK * 2 * 4);
  int*   token_of = (int*)alloc((size_t)CAP * 4);
  float* wt_of    = (float*)alloc((size_t)CAP * 4);
  int*   cntcur   = (int*)alloc(64);      // cnt = cntcur[0..7], cursor = cntcur[8..15]
  if (off > ws_size) return;

  int* cnt = cntcur;
  int* cursor = cntcur + 8;

  hipMemsetAsync(cntcur, 0, 64, stream);
  hipMemsetAsync(token_of, 0xFF, (size_t)CAP * 4, stream);
  hipMemsetAsync(out, 0, (size_t)TOK * DDIM * 4, stream);

  transpose_cvt<<<dim3(HDIM / 64, DDIM / 64, NEXP), 256, 0, stream>>>(W1, w1t, DDIM, HDIM);
  transpose_cvt<<<dim3(DDIM / 64, HDIM / 64, NEXP), 256, 0, stream>>>(W2, w2t, HDIM, DDIM);
  gate_kernel<<<TOK, 64, 0, stream>>>(x, Wg, bg, xb, topi, topw, cnt);
  assign_kernel<<<(TOK * 2) / 256, 256, 0, stream>>>(topi, topw, cnt, cursor,
                                                     token_of, wt_of);

  moe_gemm<true, true, HDIM, DDIM><<<dim3(HDIM / BN, NMT), 256, 0, stream>>>(
      xb, w1t, b1, h, nullptr, cnt, token_of, wt_of);
  moe_gemm<false, false, DDIM, HDIM><<<dim3(DDIM / BN, NMT), 256, 0, stream>>>(
      h, w2t, b2, nullptr, out, cnt, token_of, wt_of);
}

// Round 5
// 756.674 us; speedup vs baseline: 1.3004x; 1.0987x over previous
//
#include <hip/hip_runtime.h>
#include <math.h>

#define TOK   8192
#define DDIM  1024
#define HDIM  4096
#define NEXP  8
#define CAP   18432   /* 16384 + 8*256 = 72*256 */
#define NMT   72
#define BM    256
#define BN    256

typedef __attribute__((ext_vector_type(8))) short  bfrag;
typedef __attribute__((ext_vector_type(4))) float  ffrag;
typedef __attribute__((ext_vector_type(8))) unsigned short us8;

__device__ __forceinline__ unsigned short f2bf(float f) {
  unsigned int u = __float_as_uint(f);
  u = (u + 0x7FFFu + ((u >> 16) & 1u)) >> 16;   // RNE
  return (unsigned short)u;
}
__device__ __forceinline__ float bf2f(unsigned short u) {
  return __uint_as_float((unsigned int)u << 16);
}

__device__ __forceinline__ void gll16(const void* g, void* l) {
  __builtin_amdgcn_global_load_lds(
      (const __attribute__((address_space(1))) unsigned int*)g,
      (__attribute__((address_space(3))) unsigned int*)l,
      16, 0, 0);
}

// ---------------- W [R][C] fp32 -> WT [C][R] bf16 (per expert batch z) -------
__global__ __launch_bounds__(256) void transpose_cvt(const float* __restrict__ in,
                                                     unsigned short* __restrict__ out,
                                                     int R, int C) {
  const size_t bo = (size_t)blockIdx.z * R * C;
  in += bo; out += bo;
  int r0 = blockIdx.y * 64, c0 = blockIdx.x * 64;
  __shared__ float t[64][65];
  int tr  = threadIdx.x >> 4;
  int tc4 = (threadIdx.x & 15) * 4;
#pragma unroll
  for (int it = 0; it < 4; ++it) {
    int r = tr + it * 16;
    float4 v = *(const float4*)&in[(size_t)(r0 + r) * C + c0 + tc4];
    t[r][tc4 + 0] = v.x; t[r][tc4 + 1] = v.y; t[r][tc4 + 2] = v.z; t[r][tc4 + 3] = v.w;
  }
  __syncthreads();
#pragma unroll
  for (int it = 0; it < 4; ++it) {
    int oc = tr + it * 16;
    int og = tc4;
    ushort4 o = { f2bf(t[og + 0][oc]), f2bf(t[og + 1][oc]),
                  f2bf(t[og + 2][oc]), f2bf(t[og + 3][oc]) };
    *(ushort4*)&out[(size_t)(c0 + oc) * R + r0 + og] = o;
  }
}

// ------- gate: logits, top-2, softmax, histogram; fused x fp32->bf16 -------
__global__ __launch_bounds__(64) void gate_kernel(const float* __restrict__ x,
                                                  const float* __restrict__ Wg,
                                                  const float* __restrict__ bg,
                                                  unsigned short* __restrict__ xb,
                                                  int* __restrict__ topi,
                                                  float* __restrict__ topw,
                                                  int* __restrict__ cnt) {
  int t = blockIdx.x, l = threadIdx.x;
  const float4* xr = (const float4*)(x + (size_t)t * DDIM);
  ushort4* xo = (ushort4*)(xb + (size_t)t * DDIM);
  const float4* wg = (const float4*)Wg;
  float acc[8];
#pragma unroll
  for (int e = 0; e < 8; ++e) acc[e] = 0.f;
#pragma unroll
  for (int g = 0; g < 4; ++g) {
    int idx = g * 64 + l;
    float4 xv = xr[idx];
    xo[idx] = (ushort4){ f2bf(xv.x), f2bf(xv.y), f2bf(xv.z), f2bf(xv.w) };
    int dbase = idx * 4;
    float xs[4] = { xv.x, xv.y, xv.z, xv.w };
#pragma unroll
    for (int c = 0; c < 4; ++c) {
      float4 w0 = wg[(dbase + c) * 2 + 0];
      float4 w1 = wg[(dbase + c) * 2 + 1];
      acc[0] += xs[c] * w0.x; acc[1] += xs[c] * w0.y;
      acc[2] += xs[c] * w0.z; acc[3] += xs[c] * w0.w;
      acc[4] += xs[c] * w1.x; acc[5] += xs[c] * w1.y;
      acc[6] += xs[c] * w1.z; acc[7] += xs[c] * w1.w;
    }
  }
#pragma unroll
  for (int off = 32; off >= 1; off >>= 1)
#pragma unroll
    for (int e = 0; e < 8; ++e) acc[e] += __shfl_down(acc[e], off);
  if (l == 0) {
    float v[8];
#pragma unroll
    for (int e = 0; e < 8; ++e) v[e] = acc[e] + bg[e];
    int i0 = 0;
#pragma unroll
    for (int e = 1; e < 8; ++e) if (v[e] > v[i0]) i0 = e;
    int i1 = -1;
#pragma unroll
    for (int e = 0; e < 8; ++e) if (e != i0 && (i1 < 0 || v[e] > v[i1])) i1 = e;
    float e1 = expf(v[i1] - v[i0]);
    float s = 1.f + e1;
    topi[t * 2 + 0] = i0; topi[t * 2 + 1] = i1;
    topw[t * 2 + 0] = 1.f / s; topw[t * 2 + 1] = e1 / s;
    atomicAdd(&cnt[i0], 1);
    atomicAdd(&cnt[i1], 1);
  }
}

// local 256-aligned exclusive scan of cnt (uniform, 8 entries)
__device__ __forceinline__ void local_scan(const int* __restrict__ cnt, int* offs) {
  int o = 0;
#pragma unroll
  for (int e = 0; e < NEXP; ++e) {
    offs[e] = o;
    o += ((cnt[e] + 255) >> 8) << 8;
  }
  offs[NEXP] = o;
}

// ---------------- assign rows ----------------
__global__ __launch_bounds__(256) void assign_kernel(const int* __restrict__ topi,
                                                     const int* __restrict__ cnt,
                                                     int* __restrict__ cursor,
                                                     int* __restrict__ row_of,
                                                     int* __restrict__ token_of) {
  int offs[NEXP + 1];
  local_scan(cnt, offs);
  int id = blockIdx.x * 256 + threadIdx.x;
  if (id >= TOK * 2) return;
  int e = topi[id];
  int slot = atomicAdd(&cursor[e], 1);
  int row = offs[e] + slot;
  row_of[id] = row;
  token_of[row] = id >> 1;
}

// ---- grouped GEMM: 256x256, BK=64, 4-phase counted-vmcnt pipeline ----
// A: bf16 [rows][K] (INDIRECT: tile row -> token_of gather)
// B: bf16 [NEXP][N][K] (k-contiguous)
// out: bf16 [rows][N] = GELU ? gelu(acc+bias) : acc+bias, LDS-staged coalesced.
// LDS: A tiles [2buf][256r][128B] at 0..64K, B same at 64K..128K.
// Read-side XOR swizzle (chunk ^= row&7) with inverse-swizzled global source.
template<bool INDIRECT, bool GELU, int N, int K>
__global__ __launch_bounds__(512)
void moe_gemm(const unsigned short* __restrict__ A,
              const unsigned short* __restrict__ B0,
              const float* __restrict__ bias0,
              unsigned short* __restrict__ out,
              const int* __restrict__ cnt,
              const int* __restrict__ token_of) {
  int offs[NEXP + 1];
  local_scan(cnt, offs);

  // XCD-chunked bijective swizzle (nwg % 8 == 0 for both grids)
  int nwg = gridDim.x * gridDim.y;
  int orig = blockIdx.y * gridDim.x + blockIdx.x;
  int vid = (orig & 7) * (nwg >> 3) + (orig >> 3);
  int bx = vid % gridDim.x, by = vid / gridDim.x;

  int row0 = by * BM;
  if (row0 >= offs[NEXP]) return;
  int e = 0;
  while (row0 >= offs[e + 1]) ++e;
  const unsigned short* Bp = B0 + (size_t)e * N * K;
  const float* bias = bias0 + (size_t)e * N;
  int n0 = bx * BN;

  __shared__ __align__(16) char sm[131072];

  int tid = threadIdx.x;
  int w = tid >> 6, l = tid & 63;
  int lrow = l & 15, kq = l >> 4;
  int wm = w & 1, wn = w >> 1;            // 2M x 4N waves; per-wave C = 128x64
  int csw = ((l & 7) ^ (l >> 3)) * 16;    // inverse-swizzled byte col in 128B row

  // staging sources. A-half h = rows with bit6==h of each 128-row wave stripe
  // (first-used at phase h). B-half h = cols with bit5==h of each 64-col wave
  // stripe (first-used at phases 0 / 2).
  const char* srcA[2][2];
  const char* srcB[2][2];
#pragma unroll
  for (int h = 0; h < 2; ++h)
#pragma unroll
    for (int j = 0; j < 2; ++j) {
      int gr = h * 64 + j * 128 + w * 8 + (l >> 3);
      int ar;
      if (INDIRECT) { int t0 = token_of[row0 + gr]; ar = t0 < 0 ? 0 : t0; }
      else ar = row0 + gr;
      srcA[h][j] = (const char*)(A + (size_t)ar * K) + csw;
      int bb = w + j * 8;
      int grB = (bb >> 2) * 64 + h * 32 + (bb & 3) * 8 + (l >> 3);
      srcB[h][j] = (const char*)(Bp + (size_t)(n0 + grB) * K) + csw;
    }

  auto issueA = [&](int t, int h) {
    int bufo = (t & 1) * 32768;
    int kb = t * 128;
#pragma unroll
    for (int j = 0; j < 2; ++j)
      gll16(srcA[h][j] + kb, sm + bufo + (h * 64 + j * 128 + w * 8) * 128);
  };
  auto issueB = [&](int t, int h) {
    int bufo = (t & 1) * 32768;
    int kb = t * 128;
#pragma unroll
    for (int j = 0; j < 2; ++j) {
      int bb = w + j * 8;
      gll16(srcB[h][j] + kb,
            sm + 65536 + bufo + ((bb >> 2) * 64 + h * 32 + (bb & 3) * 8) * 128);
    }
  };
  auto rdA = [&](int bufo, int mi, int ks) -> bfrag {
    int row = wm * 128 + mi * 16 + lrow;
    int cc = (ks * 4 + kq) ^ (row & 7);
    return *(const bfrag*)(sm + bufo + row * 128 + cc * 16);
  };
  auto rdB = [&](int bufo, int nj, int ks) -> bfrag {
    int row = wn * 64 + nj * 16 + lrow;
    int cc = (ks * 4 + kq) ^ (row & 7);
    return *(const bfrag*)(sm + 65536 + bufo + row * 128 + cc * 16);
  };

  ffrag acc[8][4];
#pragma unroll
  for (int i = 0; i < 8; ++i)
#pragma unroll
    for (int j = 0; j < 4; ++j) acc[i][j] = (ffrag){0.f, 0.f, 0.f, 0.f};

  // prologue: tile 0, issue order A0 B0 A1 B1; need A0,B0 before phase 0.
  issueA(0, 0); issueB(0, 0); issueA(0, 1); issueB(0, 1);
  asm volatile("s_waitcnt vmcnt(4)" ::: "memory");
  __builtin_amdgcn_s_barrier();

  bfrag a[4][2], b[2][2];
  const int NT = K / 64;

#define MFMA_Q(MOFF, NOFF)                                                        \
  __builtin_amdgcn_s_setprio(1);                                                  \
  _Pragma("unroll")                                                               \
  for (int mi = 0; mi < 4; ++mi)                                                  \
    _Pragma("unroll")                                                             \
    for (int nj = 0; nj < 2; ++nj) {                                              \
      acc[mi + MOFF][nj + NOFF] = __builtin_amdgcn_mfma_f32_16x16x32_bf16(        \
          a[mi][0], b[nj][0], acc[mi + MOFF][nj + NOFF], 0, 0, 0);                \
      acc[mi + MOFF][nj + NOFF] = __builtin_amdgcn_mfma_f32_16x16x32_bf16(        \
          a[mi][1], b[nj][1], acc[mi + MOFF][nj + NOFF], 0, 0, 0);                \
    }                                                                             \
  __builtin_amdgcn_s_setprio(0);

  for (int t = 0; t < NT; ++t) {
    const int bufo = (t & 1) * 32768;
    const bool pre = (t + 1 < NT);
    // phase 0: quad (rows lo, cols lo); reads A-h0, B-h0
#pragma unroll
    for (int mi = 0; mi < 4; ++mi) { a[mi][0] = rdA(bufo, mi, 0); a[mi][1] = rdA(bufo, mi, 1); }
#pragma unroll
    for (int nj = 0; nj < 2; ++nj) { b[nj][0] = rdB(bufo, nj, 0); b[nj][1] = rdB(bufo, nj, 1); }
    if (pre) { issueA(t + 1, 0); asm volatile("s_waitcnt vmcnt(4)" ::: "memory"); }
    else     {                   asm volatile("s_waitcnt vmcnt(2)" ::: "memory"); }
    __builtin_amdgcn_s_barrier();
    MFMA_Q(0, 0)
    __builtin_amdgcn_s_barrier();
    // phase 1: rows hi (reads A-h1), reuse b
#pragma unroll
    for (int mi = 0; mi < 4; ++mi) { a[mi][0] = rdA(bufo, mi + 4, 0); a[mi][1] = rdA(bufo, mi + 4, 1); }
    if (pre) { issueB(t + 1, 0); asm volatile("s_waitcnt vmcnt(4)" ::: "memory"); }
    else     {                   asm volatile("s_waitcnt vmcnt(0)" ::: "memory"); }
    __builtin_amdgcn_s_barrier();
    MFMA_Q(4, 0)
    __builtin_amdgcn_s_barrier();
    // phase 2: cols hi (reads B-h1), reuse a
#pragma unroll
    for (int nj = 0; nj < 2; ++nj) { b[nj][0] = rdB(bufo, nj + 2, 0); b[nj][1] = rdB(bufo, nj + 2, 1); }
    if (pre) issueA(t + 1, 1);
    __builtin_amdgcn_s_barrier();
    MFMA_Q(4, 2)
    __builtin_amdgcn_s_barrier();
    // phase 3: rows lo again (re-read A-h0), reuse b
#pragma unroll
    for (int mi = 0; mi < 4; ++mi) { a[mi][0] = rdA(bufo, mi, 0); a[mi][1] = rdA(bufo, mi, 1); }
    if (pre) { issueB(t + 1, 1); asm volatile("s_waitcnt vmcnt(4)" ::: "memory"); }
    __builtin_amdgcn_s_barrier();
    MFMA_Q(0, 2)
    __builtin_amdgcn_s_barrier();
  }
#undef MFMA_Q

  // epilogue: bias (+gelu), bf16, LDS-staged coalesced store
  __syncthreads();
  unsigned short* ht = (unsigned short*)sm;   // [256][256] bf16 = 128 KB
#pragma unroll
  for (int nj = 0; nj < 4; ++nj) {
    int col = wn * 64 + nj * 16 + lrow;
    float bj = bias[n0 + col];
#pragma unroll
    for (int mi = 0; mi < 8; ++mi) {
      int rl = wm * 128 + mi * 16 + kq * 4;
#pragma unroll
      for (int r = 0; r < 4; ++r) {
        float v = acc[mi][nj][r] + bj;
        if (GELU) {
          float z = 1.5957691216f * (v + 0.044715f * v * v * v);
          v = v / (1.0f + __expf(-z));
        }
        ht[(rl + r) * 256 + col] = f2bf(v);
      }
    }
  }
  __syncthreads();
#pragma unroll
  for (int it = 0; it < 16; ++it) {
    int s = it * 512 + tid;
    int row = s >> 5, c = (s & 31) * 8;
    us8 v = *(const us8*)(ht + row * 256 + c);
    *(us8*)&out[(size_t)(row0 + row) * N + n0 + c] = v;
  }
}

// ---------------- combine (y is bf16) ----------------
__global__ __launch_bounds__(256) void combine_kernel(const unsigned short* __restrict__ y,
                                                      const int* __restrict__ row_of,
                                                      const float* __restrict__ topw,
                                                      float* __restrict__ out) {
  int t = blockIdx.x;
  int r0 = row_of[t * 2 + 0], r1 = row_of[t * 2 + 1];
  float w0 = topw[t * 2 + 0], w1 = topw[t * 2 + 1];
  const ushort4* y0 = (const ushort4*)(y + (size_t)r0 * DDIM);
  const ushort4* y1 = (const ushort4*)(y + (size_t)r1 * DDIM);
  float4* o = (float4*)(out + (size_t)t * DDIM);
  int i = threadIdx.x;
  ushort4 a = y0[i], b = y1[i];
  float4 r = { w0 * bf2f(a.x) + w1 * bf2f(b.x), w0 * bf2f(a.y) + w1 * bf2f(b.y),
               w0 * bf2f(a.z) + w1 * bf2f(b.z), w0 * bf2f(a.w) + w1 * bf2f(b.w) };
  o[i] = r;
}

extern "C" void kernel_launch(void* const* d_in, const int* in_sizes, int n_in,
                              void* d_out, int out_size, void* d_ws, size_t ws_size,
                              hipStream_t stream) {
  const float* x  = (const float*)d_in[0];
  const float* Wg = (const float*)d_in[1];
  const float* bg = (const float*)d_in[2];
  const float* W1 = (const float*)d_in[3];
  const float* b1 = (const float*)d_in[4];
  const float* W2 = (const float*)d_in[5];
  const float* b2 = (const float*)d_in[6];
  float* out = (float*)d_out;

  size_t off = 0;
  char* base = (char*)d_ws;
  auto alloc = [&](size_t bytes) -> void* {
    void* p = base + off;
    off += (bytes + 255) & ~(size_t)255;
    return p;
  };
  unsigned short* xb  = (unsigned short*)alloc((size_t)TOK * DDIM * 2);
  unsigned short* w1t = (unsigned short*)alloc((size_t)NEXP * HDIM * DDIM * 2);
  unsigned short* w2t = (unsigned short*)alloc((size_t)NEXP * DDIM * HDIM * 2);
  unsigned short* h   = (unsigned short*)alloc((size_t)CAP * HDIM * 2);
  unsigned short* y   = (unsigned short*)alloc((size_t)CAP * DDIM * 2);
  int*   topi     = (int*)alloc((size_t)TOK * 2 * 4);
  float* topw     = (float*)alloc((size_t)TOK * 2 * 4);
  int*   row_of   = (int*)alloc((size_t)TOK * 2 * 4);
  int*   token_of = (int*)alloc((size_t)CAP * 4);
  int*   cntcur   = (int*)alloc(64);      // cnt = [0..7], cursor = [8..15]
  if (off > ws_size) return;

  int* cnt = cntcur;
  int* cursor = cntcur + 8;

  hipMemsetAsync(cntcur, 0, 64, stream);
  hipMemsetAsync(token_of, 0xFF, (size_t)CAP * 4, stream);

  transpose_cvt<<<dim3(HDIM / 64, DDIM / 64, NEXP), 256, 0, stream>>>(W1, w1t, DDIM, HDIM);
  transpose_cvt<<<dim3(DDIM / 64, HDIM / 64, NEXP), 256, 0, stream>>>(W2, w2t, HDIM, DDIM);
  gate_kernel<<<TOK, 64, 0, stream>>>(x, Wg, bg, xb, topi, topw, cnt);
  assign_kernel<<<(TOK * 2) / 256, 256, 0, stream>>>(topi, cnt, cursor, row_of, token_of);

  moe_gemm<true, true, HDIM, DDIM><<<dim3(HDIM / BN, NMT), 512, 0, stream>>>(
      xb, w1t, b1, h, cnt, token_of);
  moe_gemm<false, false, DDIM, HDIM><<<dim3(DDIM / BN, NMT), 512, 0, stream>>>(
      h, w2t, b2, y, cnt, token_of);

  combine_kernel<<<TOK, 256, 0, stream>>>(y, row_of, topw, out);
}